// Round 9
// baseline (141.997 us; speedup 1.0000x reference)
//
#include <hip/hip_runtime.h>

constexpr int B = 4, C = 16, H = 512, W = 512;
constexpr int HW = H * W;
constexpr int TS = 32, TX = 16, TYN = 16;
constexpr int NBINS = B * TYN * TX;   // 1024 tiles
constexpr int RAD = 48, WIN = 128;    // source window per tile (covers |flow|<=47)
constexpr float FR = 47.0f;
constexpr int CHUNK = 1024;           // LDS staging entries per flush
constexpr int FAR_CAP = B * HW;       // far list holds every pixel -> overflow impossible

__device__ __forceinline__ void fadd(float* p, float v) { unsafeAtomicAdd(p, v); }

// round-to-nearest-even f32 -> bf16
__device__ __forceinline__ unsigned f2bf(float x) {
    unsigned u = __float_as_uint(x);
    return (u + 0x7FFFu + ((u >> 16) & 1u)) >> 16;
}
__device__ __forceinline__ float bf_lo(unsigned w) { return __uint_as_float(w << 16); }
__device__ __forceinline__ float bf_hi(unsigned w) { return __uint_as_float(w & 0xFFFF0000u); }

// ---------------- far-flier side list (|flow| > FR; statistically ~5 pixels) ----------------
__global__ __launch_bounds__(256) void far_bin_kernel(
    const float* __restrict__ flow,
    unsigned* __restrict__ far_cnt, unsigned* __restrict__ far_list)
{
    int idx = blockIdx.x * 256 + threadIdx.x;   // exact grid
    float2 f = reinterpret_cast<const float2*>(flow)[idx];
    if (fabsf(f.x) <= FR && fabsf(f.y) <= FR) return;   // main scan covers these
    int sx = idx & (W - 1);
    int sy = (idx >> 9) & (H - 1);
    int b  = idx >> 18;
    float xd = (float)sx + f.x, yd = (float)sy + f.y;
    float xff = floorf(xd), yff = floorf(yd);
    if (!(xff >= 0.0f && yff >= 0.0f &&
          xff <= (float)(W - 2) && yff <= (float)(H - 2))) return;
    unsigned pos = atomicAdd(far_cnt, 1u);      // pos < FAR_CAP by construction
    far_list[pos] = ((unsigned)b << 18) | (unsigned)(sy * W + sx);
}

// ---------------- single-pass tile-pull kernel ----------------
__global__ __launch_bounds__(256) void warp_pull_kernel(
    const float* __restrict__ flow, const float* __restrict__ im0,
    const unsigned* __restrict__ far_cnt, const unsigned* __restrict__ far_list,
    float* __restrict__ out)
{
    __shared__ unsigned eA[CHUNK];            // lxp(6) | lyp(6)<<6 | mask(4)<<12 | winpos(14)<<16
    __shared__ unsigned eVB[CHUNK][9];        // [0..7]=bf16x2 values; [8]=ax14|ay14<<14 (far: s pre-value)
    __shared__ unsigned cnt_s[TS * TS];
    __shared__ unsigned short offs_s[TS * TS];
    __shared__ unsigned short ids[4 * CHUNK]; // entry(10b) | corner(2b)
    __shared__ unsigned wscan[4];
    __shared__ unsigned ncur_s;

    const int tid  = threadIdx.x;
    const int lane = tid & 63;
    const int wv   = tid >> 6;
    // XCD-aware swizzle (1024 % 8 == 0 -> bijective): window overlap stays in-XCD L2
    const int bin = ((int)blockIdx.x & 7) * (NBINS / 8) + ((int)blockIdx.x >> 3);
    const int b  = bin >> 8;
    const int ty = (bin >> 4) & 15;
    const int tx = bin & 15;
    const int y0 = ty * TS, x0 = tx * TS;
    const int wy0 = y0 - RAD, wx0 = x0 - RAD;

    const float2* flowb = reinterpret_cast<const float2*>(flow) + (size_t)b * HW;
    const float*  im0b  = im0 + (size_t)b * C * HW;

    float acc[4][16];
    #pragma unroll
    for (int j = 0; j < 4; ++j)
        #pragma unroll
        for (int c = 0; c < 16; ++c) acc[j][c] = 0.0f;

    if (tid == 0) ncur_s = 0u;
    __syncthreads();

    // wave-aggregated append to the shared list (single cursor)
    auto append = [&](bool contrib, unsigned A, unsigned Bw) {
        unsigned long long bal = __ballot(contrib);
        if (bal) {
            unsigned cw = (unsigned)__popcll(bal);
            unsigned basew = 0;
            if (lane == 0) basew = atomicAdd(&ncur_s, cw);
            basew = (unsigned)__shfl((int)basew, 0);
            if (contrib) {
                unsigned slot = basew + (unsigned)__popcll(bal & ((1ull << lane) - 1ull));
                eA[slot] = A;
                eVB[slot][8] = Bw;
            }
        }
    };

    // process current list: load values, build per-cell lists, gather into acc
    auto flushfn = [&](int n, bool farm) {
        #pragma unroll
        for (int j = 0; j < 4; ++j) cnt_s[tid + 256 * j] = 0u;
        // value phase
        for (int i = tid; i < n; i += 256) {
            int s;
            if (!farm) {
                unsigned wp = eA[i] >> 16;
                int ry = (int)(wp >> 7), rx = (int)(wp & 127u);
                s = (wy0 + ry) * W + (wx0 + rx);
            } else {
                s = (int)eVB[i][8];
                int sxx = s & (W - 1), syy = s >> 9;
                float2 f = flowb[s];
                float xd = (float)sxx + f.x, yd = (float)syy + f.y;
                float ax = xd - floorf(xd), ay = yd - floorf(yd);
                unsigned ax14 = min((unsigned)(ax * 16384.0f), 16383u);
                unsigned ay14 = min((unsigned)(ay * 16384.0f), 16383u);
                eVB[i][8] = ax14 | (ay14 << 14);
            }
            const float* p = im0b + s;
            #pragma unroll
            for (int cp = 0; cp < 8; ++cp) {
                float v0 = p[(size_t)(2 * cp)     * HW];
                float v1 = p[(size_t)(2 * cp + 1) * HW];
                eVB[i][cp] = f2bf(v0) | (f2bf(v1) << 16);
            }
        }
        __syncthreads();
        // count corner contributions per cell
        for (int i = tid; i < n; i += 256) {
            unsigned A = eA[i];
            int lxp = (int)(A & 63u), lyp = (int)((A >> 6) & 63u);
            unsigned mask = (A >> 12) & 15u;
            #pragma unroll
            for (int corner = 0; corner < 4; ++corner)
                if (mask & (1u << corner)) {
                    int cell = (lyp - 1 + (corner >> 1)) * TS + (lxp - 1 + (corner & 1));
                    atomicAdd(&cnt_s[cell], 1u);
                }
        }
        __syncthreads();
        // block prefix scan (4 cells/thread)
        unsigned c0 = cnt_s[4 * tid], c1 = cnt_s[4 * tid + 1];
        unsigned c2 = cnt_s[4 * tid + 2], c3 = cnt_s[4 * tid + 3];
        unsigned s4 = c0 + c1 + c2 + c3, ps = s4;
        #pragma unroll
        for (int d = 1; d < 64; d <<= 1) {
            unsigned o = __shfl_up(ps, d, 64);
            if (lane >= d) ps += o;
        }
        if (lane == 63) wscan[wv] = ps;
        __syncthreads();
        if (tid == 0) {
            unsigned a = 0;
            for (int w_ = 0; w_ < 4; ++w_) { unsigned t_ = wscan[w_]; wscan[w_] = a; a += t_; }
        }
        __syncthreads();
        unsigned base = wscan[wv] + ps - s4;
        offs_s[4 * tid]     = (unsigned short)base;                  cnt_s[4 * tid]     = base;
        offs_s[4 * tid + 1] = (unsigned short)(base + c0);           cnt_s[4 * tid + 1] = base + c0;
        offs_s[4 * tid + 2] = (unsigned short)(base + c0 + c1);      cnt_s[4 * tid + 2] = base + c0 + c1;
        offs_s[4 * tid + 3] = (unsigned short)(base + c0 + c1 + c2); cnt_s[4 * tid + 3] = base + c0 + c1 + c2;
        __syncthreads();
        // place contributor ids
        for (int i = tid; i < n; i += 256) {
            unsigned A = eA[i];
            int lxp = (int)(A & 63u), lyp = (int)((A >> 6) & 63u);
            unsigned mask = (A >> 12) & 15u;
            #pragma unroll
            for (int corner = 0; corner < 4; ++corner)
                if (mask & (1u << corner)) {
                    int cell = (lyp - 1 + (corner >> 1)) * TS + (lxp - 1 + (corner & 1));
                    unsigned slot = atomicAdd(&cnt_s[cell], 1u);
                    ids[slot] = (unsigned short)((unsigned)i | ((unsigned)corner << 10));
                }
        }
        __syncthreads();
        // gather into register accumulators
        #pragma unroll
        for (int j = 0; j < 4; ++j) {
            int cell = tid + 256 * j;
            int k0 = (int)offs_s[cell], k1 = (int)cnt_s[cell];
            for (int k = k0; k < k1; ++k) {
                unsigned id2 = ids[k];
                unsigned e = id2 & 1023u;
                unsigned corner = id2 >> 10;
                unsigned wt = eVB[e][8];
                float ax = (float)(wt & 0x3FFFu) * (1.0f / 16384.0f);
                float ay = (float)((wt >> 14) & 0x3FFFu) * (1.0f / 16384.0f);
                float fx = (corner & 1u) ? ax : 1.0f - ax;
                float fy = (corner & 2u) ? ay : 1.0f - ay;
                float wgt = fx * fy;
                #pragma unroll
                for (int cp = 0; cp < 8; ++cp) {
                    unsigned vw = eVB[e][cp];
                    acc[j][2 * cp]     += wgt * bf_lo(vw);
                    acc[j][2 * cp + 1] += wgt * bf_hi(vw);
                }
            }
        }
        __syncthreads();
        if (tid == 0) ncur_s = 0u;
        __syncthreads();
    };

    // ---- main scan: 32 segments x 512 probes over the 128x128 window ----
    for (int seg = 0; seg < 32; ++seg) {
        #pragma unroll
        for (int p = 0; p < 2; ++p) {
            int i  = seg * 512 + p * 256 + tid;
            int ry = i >> 7, rx = i & 127;
            int sy = wy0 + ry, sx = wx0 + rx;
            bool contrib = false; unsigned A = 0, Bw = 0;
            if ((unsigned)sy < (unsigned)H && (unsigned)sx < (unsigned)W) {
                float2 f = flowb[sy * W + sx];
                if (fabsf(f.x) <= FR && fabsf(f.y) <= FR) {
                    float xd = (float)sx + f.x, yd = (float)sy + f.y;
                    float xff = floorf(xd), yff = floorf(yd);
                    if (xff >= 0.0f && yff >= 0.0f &&
                        xff <= (float)(W - 2) && yff <= (float)(H - 2)) {
                        int xf = (int)xff, yf = (int)yff;
                        int lx = xf - x0, ly = yf - y0;
                        bool ix0 = (unsigned)lx < 32u, ix1 = (unsigned)(lx + 1) < 32u;
                        bool iy0 = (unsigned)ly < 32u, iy1 = (unsigned)(ly + 1) < 32u;
                        unsigned mask = (unsigned)(ix0 && iy0) | ((unsigned)(ix1 && iy0) << 1)
                                      | ((unsigned)(ix0 && iy1) << 2) | ((unsigned)(ix1 && iy1) << 3);
                        if (mask) {
                            float ax = xd - xff, ay = yd - yff;
                            unsigned ax14 = min((unsigned)(ax * 16384.0f), 16383u);
                            unsigned ay14 = min((unsigned)(ay * 16384.0f), 16383u);
                            A  = (unsigned)(lx + 1) | ((unsigned)(ly + 1) << 6)
                               | (mask << 12) | ((unsigned)i << 16);
                            Bw = ax14 | (ay14 << 14);
                            contrib = true;
                        }
                    }
                }
            }
            append(contrib, A, Bw);
        }
        __syncthreads();
        int nc = (int)ncur_s;
        __syncthreads();
        if (nc > CHUNK - 512 || seg == 31) { if (nc > 0) flushfn(nc, false); }
    }

    // ---- far-flier phase (list is ~empty in practice) ----
    const int nf = (int)*far_cnt;
    for (int base_i = 0; base_i < nf; base_i += 256) {
        int i = base_i + tid;
        bool contrib = false; unsigned A = 0, Bw = 0;
        if (i < nf) {
            unsigned e = far_list[i];
            if ((int)(e >> 18) == b) {
                int s = (int)(e & 0x3FFFFu);
                int sxx = s & (W - 1), syy = s >> 9;
                float2 f = flowb[s];
                float xd = (float)sxx + f.x, yd = (float)syy + f.y;
                int xf = (int)floorf(xd), yf = (int)floorf(yd);
                int lx = xf - x0, ly = yf - y0;
                bool ix0 = (unsigned)lx < 32u, ix1 = (unsigned)(lx + 1) < 32u;
                bool iy0 = (unsigned)ly < 32u, iy1 = (unsigned)(ly + 1) < 32u;
                unsigned mask = (unsigned)(ix0 && iy0) | ((unsigned)(ix1 && iy0) << 1)
                              | ((unsigned)(ix0 && iy1) << 2) | ((unsigned)(ix1 && iy1) << 3);
                if (mask) { A = (unsigned)(lx + 1) | ((unsigned)(ly + 1) << 6) | (mask << 12);
                            Bw = (unsigned)s; contrib = true; }
            }
        }
        append(contrib, A, Bw);
        __syncthreads();
        int nc = (int)ncur_s;
        __syncthreads();
        if (nc > CHUNK - 256) flushfn(nc, true);
    }
    __syncthreads();
    { int nc = (int)ncur_s; __syncthreads(); if (nc > 0) flushfn(nc, true); }

    // ---- coalesced plain store (covers every cell: no out memset needed) ----
    size_t outb = (size_t)b * C * HW;
    #pragma unroll
    for (int j = 0; j < 4; ++j) {
        int cell = tid + 256 * j;
        int cy = cell >> 5, cx = cell & 31;
        float* op0 = out + outb + (size_t)(y0 + cy) * W + (x0 + cx);
        #pragma unroll
        for (int c = 0; c < 16; ++c) op0[(size_t)c * HW] = acc[j][c];
    }
}

// =================== FALLBACK: naive direct-atomic ===================
__global__ __launch_bounds__(256) void warp_naive_kernel(
    const float* __restrict__ im0, const float* __restrict__ flow,
    float* __restrict__ out)
{
    int idx = blockIdx.x * 256 + threadIdx.x;
    if (idx >= B * HW) return;
    int w = idx & (W - 1);
    int h = (idx >> 9) & (H - 1);
    int b = idx >> 18;
    float2 f = reinterpret_cast<const float2*>(flow)[idx];
    float xd = (float)w + f.x, yd = (float)h + f.y;
    float xff = floorf(xd), yff = floorf(yd);
    if (!(xff >= 0.0f && yff >= 0.0f &&
          xff <= (float)(W - 2) && yff <= (float)(H - 2))) return;
    int xf = (int)xff, yf = (int)yff;
    float ax = xd - xff, ay = yd - yff;
    float w0 = (1.f - ax) * (1.f - ay), w1 = ax * (1.f - ay);
    float w2 = (1.f - ax) * ay,         w3 = ax * ay;
    size_t base = (size_t)b * C * HW;
    int d00 = yf * W + xf;
    for (int c = 0; c < C; ++c) {
        float v = im0[base + (size_t)c * HW + h * W + w];
        float* o = out + base + (size_t)c * HW + d00;
        fadd(o, v * w0); fadd(o + 1, v * w1); fadd(o + W, v * w2); fadd(o + W + 1, v * w3);
    }
}

extern "C" void kernel_launch(void* const* d_in, const int* in_sizes, int n_in,
                              void* d_out, int out_size, void* d_ws, size_t ws_size,
                              hipStream_t stream) {
    const float* im0  = (const float*)d_in[0];
    const float* flow = (const float*)d_in[1];
    float* out = (float*)d_out;

    // ws layout: far_cnt (16 u32, 64B) | far_list[FAR_CAP]
    constexpr size_t need = (16 + (size_t)FAR_CAP) * 4;   // ~4.2 MB
    constexpr int total = B * HW;

    if (ws_size < need) {
        hipMemsetAsync(out, 0, (size_t)out_size * sizeof(float), stream);
        warp_naive_kernel<<<(total + 255) / 256, 256, 0, stream>>>(im0, flow, out);
        return;
    }

    unsigned* far_cnt  = (unsigned*)d_ws;
    unsigned* far_list = far_cnt + 16;
    hipMemsetAsync(far_cnt, 0, 64, stream);

    far_bin_kernel<<<total / 256, 256, 0, stream>>>(flow, far_cnt, far_list);
    warp_pull_kernel<<<NBINS, 256, 0, stream>>>(flow, im0, far_cnt, far_list, out);
}

// Round 10
// 95.005 us; speedup vs baseline: 1.4946x; 1.4946x over previous
//
#include <hip/hip_runtime.h>

constexpr int B = 4, C = 16, H = 512, W = 512;
constexpr int HW = H * W;
constexpr int TS = 32, TX = 16, TYN = 16;
constexpr int NBINS = B * TYN * TX;   // 1024
constexpr int CAP   = 1280;           // slots per bin (expected max ~1230)
constexpr int CSTR  = 16;             // counter stride in u32 -> 64B per counter
constexpr int REC   = 10;             // u32 words per value-record (40 B)
constexpr int SCAP  = 1024;           // max staged entries per block (4 per pixel hard cap)
constexpr int OVF_CAP = 65536;        // overflow side-list entries

__device__ __forceinline__ void fadd(float* p, float v) { unsafeAtomicAdd(p, v); }

// round-to-nearest-even f32 -> bf16 (upper 16 bits)
__device__ __forceinline__ unsigned f2bf(float x) {
    unsigned u = __float_as_uint(x);
    return (u + 0x7FFFu + ((u >> 16) & 1u)) >> 16;
}
__device__ __forceinline__ float bf_lo(unsigned w) { return __uint_as_float(w << 16); }
__device__ __forceinline__ float bf_hi(unsigned w) { return __uint_as_float(w & 0xFFFF0000u); }

// ---- direct global-atomic splat (fixup / fallback paths) ----
__device__ __forceinline__ void direct_splat(
    const float* __restrict__ im0, float* __restrict__ out,
    int b, int s, int xf, int yf,
    float w0, float w1, float w2, float w3, unsigned mask)
{
    size_t base = (size_t)b * C * HW;
    int d00 = yf * W + xf;
    for (int c = 0; c < C; ++c) {
        float v = im0[base + (size_t)c * HW + s];
        float* o = out + base + (size_t)c * HW + d00;
        if (mask & 1u) fadd(o,         v * w0);
        if (mask & 2u) fadd(o + 1,     v * w1);
        if (mask & 4u) fadd(o + W,     v * w2);
        if (mask & 8u) fadd(o + W + 1, v * w3);
    }
}

// =================== Phase 1: binning with COALESCED record write-out ===================
// LDS count per bin -> block prefix scan (per-bin contiguous LDS ranges) +
// one parallel global reserve per nonzero bin -> place into flat LDS staging
// -> cooperative word-linear copy-out (coalesced global writes).
__global__ __launch_bounds__(256) void bin3_kernel(
    const float* __restrict__ flow, const float* __restrict__ im0,
    unsigned* __restrict__ cnt, unsigned* __restrict__ ovf_cnt,
    unsigned* __restrict__ ovf_list, unsigned* __restrict__ entries)
{
    __shared__ unsigned lcnt[NBINS];          // count -> cursor
    __shared__ unsigned gbase[NBINS];         // block's reserved global base
    __shared__ unsigned short loff[NBINS];    // local (LDS) range start per bin
    __shared__ unsigned gidx[SCAP];           // staged entry -> global record index (~0u = ovf)
    __shared__ unsigned stage[SCAP * REC];    // 40 KB flat record staging
    __shared__ unsigned wscan[4];
    __shared__ unsigned ntot_s;

    const int tid  = threadIdx.x;
    const int lane = tid & 63;
    const int wv   = tid >> 6;

    #pragma unroll
    for (int j = 0; j < NBINS / 256; ++j) lcnt[tid + 256 * j] = 0u;
    __syncthreads();

    const int idx = blockIdx.x * 256 + tid;   // exact grid
    float2 f = reinterpret_cast<const float2*>(flow)[idx];
    int sx = idx & (W - 1);
    int sy = (idx >> 9) & (H - 1);
    int b  = idx >> 18;

    float xd = (float)sx + f.x;
    float yd = (float)sy + f.y;
    float xff = floorf(xd), yff = floorf(yd);
    bool valid = (xff >= 0.0f && yff >= 0.0f &&
                  xff <= (float)(W - 2) && yff <= (float)(H - 2));
    int xf = valid ? (int)xff : 0;
    int yf = valid ? (int)yff : 0;
    float ax = xd - xff, ay = yd - yff;

    int s = sy * W + sx;
    int d = yf * W + xf;
    unsigned ax14 = min((unsigned)(ax * 16384.0f), 16383u);
    unsigned ay14 = min((unsigned)(ay * 16384.0f), 16383u);
    unsigned meta1 = (unsigned)d | (ax14 << 18);
    unsigned ay18  = ay14 << 18;

    unsigned vw[8];
    if (valid) {
        const float* p = im0 + (size_t)b * C * HW + s;
        #pragma unroll
        for (int c = 0; c < 8; ++c) {
            float v0 = p[(size_t)(2 * c)     * HW];
            float v1 = p[(size_t)(2 * c + 1) * HW];
            vw[c] = f2bf(v0) | (f2bf(v1) << 16);
        }
    } else {
        #pragma unroll
        for (int c = 0; c < 8; ++c) vw[c] = 0;
    }

    int txf = xf >> 5, txc = (xf + 1) >> 5;
    int tyf = yf >> 5, tyc = (yf + 1) >> 5;
    bool spx = (txc != txf), spy = (tyc != tyf);
    int binb = b * (TYN * TX);

    const bool w0_ = valid, w1_ = valid && spx, w2_ = valid && spy,
               w3_ = valid && spx && spy;
    const int b0 = binb + tyf * TX + txf, b1 = binb + tyf * TX + txc;
    const int b2 = binb + tyc * TX + txf, b3 = binb + tyc * TX + txc;
    const unsigned m0 = 1u | (spx ? 0u : 2u) | (spy ? 0u : 4u) | ((!spx && !spy) ? 8u : 0u);
    const unsigned m1 = 2u | (spy ? 0u : 8u);
    const unsigned m2 = 4u | (spx ? 0u : 8u);
    const unsigned m3 = 8u;

    // ---- count ----
    if (w0_) atomicAdd(&lcnt[b0], 1u);
    if (w1_) atomicAdd(&lcnt[b1], 1u);
    if (w2_) atomicAdd(&lcnt[b2], 1u);
    if (w3_) atomicAdd(&lcnt[b3], 1u);
    __syncthreads();

    // ---- block prefix scan over 1024 bins (4/thread) + global reserve ----
    unsigned c0 = lcnt[4 * tid], c1 = lcnt[4 * tid + 1];
    unsigned c2 = lcnt[4 * tid + 2], c3 = lcnt[4 * tid + 3];
    unsigned s4 = c0 + c1 + c2 + c3, ps = s4;
    #pragma unroll
    for (int dlt = 1; dlt < 64; dlt <<= 1) {
        unsigned o = __shfl_up(ps, dlt, 64);
        if (lane >= dlt) ps += o;
    }
    if (lane == 63) wscan[wv] = ps;
    __syncthreads();
    if (tid == 0) {
        unsigned a = 0;
        #pragma unroll
        for (int w_ = 0; w_ < 4; ++w_) { unsigned t_ = wscan[w_]; wscan[w_] = a; a += t_; }
        ntot_s = a;
    }
    __syncthreads();
    unsigned lbase = wscan[wv] + ps - s4;
    {
        unsigned cc[4] = {c0, c1, c2, c3};
        unsigned run = lbase;
        #pragma unroll
        for (int q = 0; q < 4; ++q) {
            int bn = 4 * tid + q;
            unsigned gb = 0;
            if (cc[q]) gb = atomicAdd(&cnt[bn * CSTR], cc[q]);   // parallel, non-chained
            gbase[bn] = gb;
            loff[bn]  = (unsigned short)run;
            run += cc[q];
            lcnt[bn] = 0u;   // reuse as cursor
        }
    }
    __syncthreads();

    // ---- place into LDS staging (bin-ordered) ----
    unsigned ovfmask = 0;
    #pragma unroll
    for (int k = 0; k < 4; ++k) {
        bool want; int bn; unsigned mk;
        if (k == 0)      { want = w0_; bn = b0; mk = m0; }
        else if (k == 1) { want = w1_; bn = b1; mk = m1; }
        else if (k == 2) { want = w2_; bn = b2; mk = m2; }
        else             { want = w3_; bn = b3; mk = m3; }
        if (want) {
            unsigned r  = atomicAdd(&lcnt[bn], 1u);
            unsigned sl = gbase[bn] + r;
            unsigned ls = (unsigned)loff[bn] + r;
            if (sl < CAP) {
                gidx[ls] = (unsigned)bn * CAP + sl;
                unsigned* st = &stage[ls * REC];
                st[0] = meta1; st[1] = mk | ay18;
                #pragma unroll
                for (int c = 0; c < 8; ++c) st[2 + c] = vw[c];
            } else {
                gidx[ls] = 0xFFFFFFFFu;
                ovfmask |= mk;
            }
        }
    }
    if (ovfmask) {   // statistically never: queue for post-accum fixup
        unsigned o = atomicAdd(ovf_cnt, 1u);
        if (o < OVF_CAP)
            ovf_list[o] = ((unsigned)b << 22) | ((unsigned)s << 4) | ovfmask;
    }
    __syncthreads();

    // ---- coalesced copy-out: LDS flat-sequential -> global bin-contiguous ----
    const unsigned ntot = ntot_s;
    for (unsigned w = tid; w < ntot * REC; w += 256) {
        unsigned e = w / (unsigned)REC;
        unsigned k = w - e * (unsigned)REC;
        unsigned g = gidx[e];
        if (g != 0xFFFFFFFFu)
            entries[(size_t)g * REC + k] = stage[w];
    }
}

// =================== Phase 2: scatter->gather accumulation (round-8, unchanged) ===================
__global__ __launch_bounds__(256) void accum_gather_kernel(
    const unsigned* __restrict__ cnt_g, const unsigned* __restrict__ entries,
    float* __restrict__ out)
{
    __shared__ unsigned evals[CAP][9];        // [0..7]=bf16x2 vals, [8]=ax14|ay14<<14
    __shared__ unsigned cnt_s[TS * TS];       // count -> cursor -> end
    __shared__ unsigned short offs_s[TS * TS];
    __shared__ unsigned short ids[4 * CAP];   // entry id (11b) | corner (2b)
    __shared__ unsigned wscan[4];

    const int bin = blockIdx.x;
    const int tid = threadIdx.x;
    const int lane = tid & 63;
    const int wv   = tid >> 6;
    const int b  = bin >> 8;
    const int ty = (bin >> 4) & 15;
    const int tx = bin & 15;
    const int y0 = ty * TS, x0 = tx * TS;

    #pragma unroll
    for (int j = 0; j < 4; ++j) cnt_s[tid + 256 * j] = 0u;
    __syncthreads();

    const int n = min((int)cnt_g[bin * CSTR], CAP);

    // --- stage records into LDS + count corner contributions per cell ---
    unsigned dm[5];
    #pragma unroll
    for (int it = 0; it < 5; ++it) {
        int i = it * 256 + tid;
        unsigned dmv = 0;
        if (i < n) {
            const uint2* rec = reinterpret_cast<const uint2*>(
                entries + ((size_t)bin * CAP + i) * REC);
            uint2 m  = rec[0];
            uint2 q0 = rec[1], q1 = rec[2], q2 = rec[3], q3 = rec[4];
            int d = (int)(m.x & 0x3FFFFu);
            unsigned mask = m.y & 15u;
            unsigned ax14 = m.x >> 18, ay14 = m.y >> 18;
            int xf = d & (W - 1), yf = d >> 9;
            int lx = xf - x0 + 1;   // 0..32
            int ly = yf - y0 + 1;   // 0..32
            dmv = (unsigned)lx | ((unsigned)ly << 6) | (mask << 12);
            evals[i][0] = q0.x; evals[i][1] = q0.y;
            evals[i][2] = q1.x; evals[i][3] = q1.y;
            evals[i][4] = q2.x; evals[i][5] = q2.y;
            evals[i][6] = q3.x; evals[i][7] = q3.y;
            evals[i][8] = ax14 | (ay14 << 14);
            #pragma unroll
            for (int corner = 0; corner < 4; ++corner) {
                if (mask & (1u << corner)) {
                    int cell = (ly - 1 + (corner >> 1)) * TS + (lx - 1 + (corner & 1));
                    atomicAdd(&cnt_s[cell], 1u);
                }
            }
        }
        dm[it] = dmv;
    }
    __syncthreads();

    // --- block prefix scan of 1024 cell counts (4 cells/thread) ---
    unsigned c0 = cnt_s[4 * tid], c1 = cnt_s[4 * tid + 1];
    unsigned c2 = cnt_s[4 * tid + 2], c3 = cnt_s[4 * tid + 3];
    unsigned s4 = c0 + c1 + c2 + c3;
    unsigned ps = s4;
    #pragma unroll
    for (int dlt = 1; dlt < 64; dlt <<= 1) {
        unsigned o = __shfl_up(ps, dlt, 64);
        if (lane >= dlt) ps += o;
    }
    if (lane == 63) wscan[wv] = ps;
    __syncthreads();
    if (tid == 0) {
        unsigned a = 0;
        #pragma unroll
        for (int w_ = 0; w_ < 4; ++w_) { unsigned t_ = wscan[w_]; wscan[w_] = a; a += t_; }
    }
    __syncthreads();
    unsigned base = wscan[wv] + ps - s4;
    offs_s[4 * tid]     = (unsigned short)base;                  cnt_s[4 * tid]     = base;
    offs_s[4 * tid + 1] = (unsigned short)(base + c0);           cnt_s[4 * tid + 1] = base + c0;
    offs_s[4 * tid + 2] = (unsigned short)(base + c0 + c1);      cnt_s[4 * tid + 2] = base + c0 + c1;
    offs_s[4 * tid + 3] = (unsigned short)(base + c0 + c1 + c2); cnt_s[4 * tid + 3] = base + c0 + c1 + c2;
    __syncthreads();

    // --- place contributor ids (LDS cursor atomics) ---
    #pragma unroll
    for (int it = 0; it < 5; ++it) {
        int i = it * 256 + tid;
        unsigned dmv = dm[it];
        unsigned mask = dmv >> 12;
        if (i < n && mask) {
            int lx = (int)(dmv & 63u), ly = (int)((dmv >> 6) & 63u);
            #pragma unroll
            for (int corner = 0; corner < 4; ++corner) {
                if (mask & (1u << corner)) {
                    int cell = (ly - 1 + (corner >> 1)) * TS + (lx - 1 + (corner & 1));
                    unsigned slot = atomicAdd(&cnt_s[cell], 1u);
                    ids[slot] = (unsigned short)((unsigned)i | ((unsigned)corner << 11));
                }
            }
        }
    }
    __syncthreads();

    // --- gather per cell, register accumulate, coalesced plain store ---
    size_t outb = (size_t)b * C * HW;
    #pragma unroll
    for (int j = 0; j < 4; ++j) {
        int cell = tid + 256 * j;
        int cy = cell >> 5, cx = cell & 31;
        float acc[16];
        #pragma unroll
        for (int c = 0; c < 16; ++c) acc[c] = 0.0f;

        int k0 = (int)offs_s[cell];
        int k1 = (int)cnt_s[cell];
        for (int k = k0; k < k1; ++k) {
            unsigned id2 = ids[k];
            unsigned e = id2 & 0x7FFu;
            unsigned corner = id2 >> 11;
            unsigned wt = evals[e][8];
            float ax = (float)(wt & 0x3FFFu) * (1.0f / 16384.0f);
            float ay = (float)((wt >> 14) & 0x3FFFu) * (1.0f / 16384.0f);
            float fx = (corner & 1u) ? ax : 1.0f - ax;
            float fy = (corner & 2u) ? ay : 1.0f - ay;
            float wgt = fx * fy;
            #pragma unroll
            for (int cp = 0; cp < 8; ++cp) {
                unsigned vwv = evals[e][cp];
                acc[2 * cp]     += wgt * bf_lo(vwv);
                acc[2 * cp + 1] += wgt * bf_hi(vwv);
            }
        }

        float* op0 = out + outb + (size_t)(y0 + cy) * W + (x0 + cx);
        #pragma unroll
        for (int c = 0; c < 16; ++c) op0[(size_t)c * HW] = acc[c];
    }
}

// Phase 3: process overflow side-list (usually empty) AFTER plain stores.
__global__ __launch_bounds__(256) void fixup_kernel(
    const float* __restrict__ flow, const float* __restrict__ im0,
    const unsigned* __restrict__ ovf_cnt, const unsigned* __restrict__ ovf_list,
    float* __restrict__ out)
{
    unsigned n = min(*ovf_cnt, (unsigned)OVF_CAP);
    for (unsigned i = blockIdx.x * 256 + threadIdx.x; i < n; i += gridDim.x * 256) {
        unsigned e = ovf_list[i];
        int b = (int)(e >> 22);
        int s = (int)((e >> 4) & 0x3FFFFu);
        unsigned mask = e & 15u;
        int sx = s & (W - 1), sy = s >> 9;
        float2 f = reinterpret_cast<const float2*>(flow)[(size_t)b * HW + s];
        float xd = (float)sx + f.x, yd = (float)sy + f.y;
        float xff = floorf(xd), yff = floorf(yd);
        int xf = (int)xff, yf = (int)yff;
        float ax = xd - xff, ay = yd - yff;
        float w0 = (1.f - ax) * (1.f - ay), w1 = ax * (1.f - ay);
        float w2 = (1.f - ax) * ay,         w3 = ax * ay;
        direct_splat(im0, out, b, s, xf, yf, w0, w1, w2, w3, mask);
    }
}

// =================== FALLBACK: naive direct-atomic ===================
__global__ __launch_bounds__(256) void warp_naive_kernel(
    const float* __restrict__ im0, const float* __restrict__ flow,
    float* __restrict__ out)
{
    int idx = blockIdx.x * 256 + threadIdx.x;
    if (idx >= B * HW) return;
    int w = idx & (W - 1);
    int h = (idx >> 9) & (H - 1);
    int b = idx >> 18;
    float2 f = reinterpret_cast<const float2*>(flow)[idx];
    float xd = (float)w + f.x, yd = (float)h + f.y;
    float xff = floorf(xd), yff = floorf(yd);
    if (!(xff >= 0.0f && yff >= 0.0f &&
          xff <= (float)(W - 2) && yff <= (float)(H - 2))) return;
    int xf = (int)xff, yf = (int)yff;
    float ax = xd - xff, ay = yd - yff;
    float w0 = (1.f - ax) * (1.f - ay), w1 = ax * (1.f - ay);
    float w2 = (1.f - ax) * ay,         w3 = ax * ay;
    direct_splat(im0, out, b, h * W + w, xf, yf, w0, w1, w2, w3, 15u);
}

extern "C" void kernel_launch(void* const* d_in, const int* in_sizes, int n_in,
                              void* d_out, int out_size, void* d_ws, size_t ws_size,
                              hipStream_t stream) {
    const float* im0  = (const float*)d_in[0];
    const float* flow = (const float*)d_in[1];
    float* out = (float*)d_out;

    // ws layout: cnt[NBINS*CSTR] | ovf_cnt(16w) | ovf_list[OVF_CAP] | entries
    constexpr size_t cnt_words = (size_t)NBINS * CSTR;           // 16384
    constexpr size_t ovf_off   = cnt_words;
    constexpr size_t list_off  = cnt_words + 16;
    constexpr size_t ent_off   = list_off + OVF_CAP;
    constexpr size_t need_vals = (ent_off + (size_t)NBINS * CAP * REC) * 4;  // ~52.8 MB
    constexpr int total = B * HW;

    if (ws_size < need_vals) {
        hipMemsetAsync(out, 0, (size_t)out_size * sizeof(float), stream);
        warp_naive_kernel<<<(total + 255) / 256, 256, 0, stream>>>(im0, flow, out);
        return;
    }

    unsigned* cnt = (unsigned*)d_ws;
    unsigned* ovf_cnt  = cnt + ovf_off;
    unsigned* ovf_list = cnt + list_off;
    unsigned* entries  = cnt + ent_off;

    // zero bin counters + overflow counter (no out memset: accum plain-stores
    // every output element; fixup runs after)
    hipMemsetAsync(cnt, 0, list_off * 4, stream);

    bin3_kernel<<<total / 256, 256, 0, stream>>>(flow, im0, cnt, ovf_cnt, ovf_list, entries);
    accum_gather_kernel<<<NBINS, 256, 0, stream>>>(cnt, entries, out);
    fixup_kernel<<<16, 256, 0, stream>>>(flow, im0, ovf_cnt, ovf_list, out);
}

// Round 11
// 62.413 us; speedup vs baseline: 2.2751x; 1.5222x over previous
//
#include <hip/hip_runtime.h>

constexpr int B = 4, C = 16, H = 512, W = 512;
constexpr int HW = H * W;
constexpr int TS = 32, TX = 16, TYN = 16;
constexpr int NBINS = B * TYN * TX;   // 1024
constexpr int CAP   = 1280;           // slots per bin (expected max ~1230)
constexpr int CSTR  = 16;             // counter stride in u32 -> 64B per counter
constexpr int OVF_CAP = 65536;        // overflow side-list entries

__device__ __forceinline__ void fadd(float* p, float v) { unsafeAtomicAdd(p, v); }

// round-to-nearest-even f32 -> bf16 (upper 16 bits)
__device__ __forceinline__ unsigned f2bf(float x) {
    unsigned u = __float_as_uint(x);
    return (u + 0x7FFFu + ((u >> 16) & 1u)) >> 16;
}
__device__ __forceinline__ float bf_lo(unsigned w) { return __uint_as_float(w << 16); }
__device__ __forceinline__ float bf_hi(unsigned w) { return __uint_as_float(w & 0xFFFF0000u); }

// ---- direct global-atomic splat (fixup / fallback paths) ----
__device__ __forceinline__ void direct_splat(
    const float* __restrict__ im0, float* __restrict__ out,
    int b, int s, int xf, int yf,
    float w0, float w1, float w2, float w3, unsigned mask)
{
    size_t base = (size_t)b * C * HW;
    int d00 = yf * W + xf;
    for (int c = 0; c < C; ++c) {
        float v = im0[base + (size_t)c * HW + s];
        float* o = out + base + (size_t)c * HW + d00;
        if (mask & 1u) fadd(o,         v * w0);
        if (mask & 2u) fadd(o + 1,     v * w1);
        if (mask & 4u) fadd(o + W,     v * w2);
        if (mask & 8u) fadd(o + W + 1, v * w3);
    }
}

// =================== Phase 1: binning (round-8 bin2 shape + SoA records) ===================
// LDS count -> one parallel global reserve per nonzero bin -> LDS-cursor place
// with direct global record writes: values plane 32B aligned (2x uint4),
// meta plane 4B (lxp|lyp|ax10|ay10; corner mask derived in accum).
__global__ __launch_bounds__(256) void bin4_kernel(
    const float* __restrict__ flow, const float* __restrict__ im0,
    unsigned* __restrict__ cnt, unsigned* __restrict__ ovf_cnt,
    unsigned* __restrict__ ovf_list,
    uint4* __restrict__ entv, unsigned* __restrict__ entm)
{
    __shared__ unsigned lcnt[NBINS];    // per-block count, then cursor
    __shared__ unsigned gbase[NBINS];   // block's reserved global base
    const int tid = threadIdx.x;

    #pragma unroll
    for (int j = 0; j < NBINS / 256; ++j) lcnt[tid + 256 * j] = 0u;
    __syncthreads();

    const int idx = blockIdx.x * 256 + tid;   // exact grid
    float2 f = reinterpret_cast<const float2*>(flow)[idx];
    int sx = idx & (W - 1);
    int sy = (idx >> 9) & (H - 1);
    int b  = idx >> 18;

    float xd = (float)sx + f.x;
    float yd = (float)sy + f.y;
    float xff = floorf(xd), yff = floorf(yd);
    bool valid = (xff >= 0.0f && yff >= 0.0f &&
                  xff <= (float)(W - 2) && yff <= (float)(H - 2));
    int xf = valid ? (int)xff : 0;
    int yf = valid ? (int)yff : 0;
    float ax = xd - xff, ay = yd - yff;

    int s = sy * W + sx;
    unsigned ax10 = min((unsigned)(ax * 1024.0f + 0.5f), 1023u);
    unsigned ay10 = min((unsigned)(ay * 1024.0f + 0.5f), 1023u);
    unsigned wbits = (ax10 << 12) | (ay10 << 22);

    // 16-channel coalesced read + bf16 pack
    unsigned vw[8];
    if (valid) {
        const float* p = im0 + (size_t)b * C * HW + s;
        #pragma unroll
        for (int c = 0; c < 8; ++c) {
            float v0 = p[(size_t)(2 * c)     * HW];
            float v1 = p[(size_t)(2 * c + 1) * HW];
            vw[c] = f2bf(v0) | (f2bf(v1) << 16);
        }
    } else {
        #pragma unroll
        for (int c = 0; c < 8; ++c) vw[c] = 0;
    }
    const uint4 V0 = make_uint4(vw[0], vw[1], vw[2], vw[3]);
    const uint4 V1 = make_uint4(vw[4], vw[5], vw[6], vw[7]);

    int txf = xf >> 5, txc = (xf + 1) >> 5;
    int tyf = yf >> 5, tyc = (yf + 1) >> 5;
    bool spx = (txc != txf), spy = (tyc != tyf);
    int binb = b * (TYN * TX);

    const bool w0_ = valid, w1_ = valid && spx, w2_ = valid && spy,
               w3_ = valid && spx && spy;
    const int b0 = binb + tyf * TX + txf, b1 = binb + tyf * TX + txc;
    const int b2 = binb + tyc * TX + txf, b3 = binb + tyc * TX + txc;
    // tile-local packed coords per bin (lxp = lx+1 in [0,33])
    const unsigned lxh = (unsigned)(xf & 31) + 1u;   // home-column bins
    const unsigned lyh = (unsigned)(yf & 31) + 1u;   // home-row bins
    const unsigned meta0 = lxh |  (lyh << 6) | wbits;  // (txf,tyf)
    const unsigned meta1 = 0u  |  (lyh << 6) | wbits;  // (txc,tyf): lxp=0
    const unsigned meta2 = lxh |  (0u  << 6) | wbits;  // (txf,tyc): lyp=0
    const unsigned meta3 = 0u  |  (0u  << 6) | wbits;  // (txc,tyc)
    // corner masks (for overflow side-list only)
    const unsigned m0 = 1u | (spx ? 0u : 2u) | (spy ? 0u : 4u) | ((!spx && !spy) ? 8u : 0u);
    const unsigned m1 = 2u | (spy ? 0u : 8u);
    const unsigned m2 = 4u | (spx ? 0u : 8u);
    const unsigned m3 = 8u;

    // ---- count (non-returning LDS atomics) ----
    if (w0_) atomicAdd(&lcnt[b0], 1u);
    if (w1_) atomicAdd(&lcnt[b1], 1u);
    if (w2_) atomicAdd(&lcnt[b2], 1u);
    if (w3_) atomicAdd(&lcnt[b3], 1u);
    __syncthreads();

    // ---- global reserve: parallel atomics by distinct threads, one round-trip ----
    #pragma unroll
    for (int j = 0; j < NBINS / 256; ++j) {
        int bn = tid + 256 * j;
        unsigned c = lcnt[bn];
        unsigned gb = 0;
        if (c) gb = atomicAdd(&cnt[bn * CSTR], c);
        gbase[bn] = gb;
        lcnt[bn] = 0u;      // reuse as cursor
    }
    __syncthreads();

    // ---- place: LDS cursor -> direct global SoA record write ----
    unsigned ovfmask = 0;
    #pragma unroll
    for (int k = 0; k < 4; ++k) {
        bool want; int bn; unsigned mt, mk;
        if (k == 0)      { want = w0_; bn = b0; mt = meta0; mk = m0; }
        else if (k == 1) { want = w1_; bn = b1; mt = meta1; mk = m1; }
        else if (k == 2) { want = w2_; bn = b2; mt = meta2; mk = m2; }
        else             { want = w3_; bn = b3; mt = meta3; mk = m3; }
        if (want) {
            unsigned r  = atomicAdd(&lcnt[bn], 1u);
            unsigned sl = gbase[bn] + r;
            if (sl < CAP) {
                size_t rec = (size_t)bn * CAP + sl;
                entv[rec * 2]     = V0;
                entv[rec * 2 + 1] = V1;
                entm[rec] = mt;
            } else {
                ovfmask |= mk;
            }
        }
    }
    if (ovfmask) {   // statistically never: queue for post-accum fixup
        unsigned o = atomicAdd(ovf_cnt, 1u);
        if (o < OVF_CAP)
            ovf_list[o] = ((unsigned)b << 22) | ((unsigned)s << 4) | ovfmask;
    }
}

// =================== Phase 2: scatter->gather accumulation (512 threads) ===================
__global__ __launch_bounds__(512) void accum2_kernel(
    const unsigned* __restrict__ cnt_g,
    const uint4* __restrict__ entv, const unsigned* __restrict__ entm,
    float* __restrict__ out)
{
    __shared__ unsigned evals[CAP][9];        // [0..7]=bf16x2 vals, [8]=ax10|ay10<<10
    __shared__ unsigned cnt_s[TS * TS];       // count -> cursor -> end
    __shared__ unsigned short offs_s[TS * TS];
    __shared__ unsigned short ids[4 * CAP];   // entry id (11b) | corner (2b)
    __shared__ unsigned wscan[8];

    const int bin = blockIdx.x;
    const int tid = threadIdx.x;
    const int lane = tid & 63;
    const int wv   = tid >> 6;
    const int b  = bin >> 8;
    const int ty = (bin >> 4) & 15;
    const int tx = bin & 15;
    const int y0 = ty * TS, x0 = tx * TS;

    #pragma unroll
    for (int j = 0; j < 2; ++j) cnt_s[tid + 512 * j] = 0u;
    __syncthreads();

    const int n = min((int)cnt_g[bin * CSTR], CAP);

    // --- stage records (coalesced uint4 loads) + derive mask + count per cell ---
    unsigned dm[3];
    #pragma unroll
    for (int it = 0; it < 3; ++it) {
        int i = it * 512 + tid;
        unsigned dmv = 0;
        if (i < n) {
            size_t rec = (size_t)bin * CAP + i;
            uint4 q0 = entv[rec * 2];
            uint4 q1 = entv[rec * 2 + 1];
            unsigned m = entm[rec];
            unsigned lxp = m & 63u, lyp = (m >> 6) & 63u;
            // derived corner ownership: corner (dx,dy) coords lx+dx in [0,32)
            bool ix0 = (lxp - 1u) < 32u, ix1 = lxp < 32u;
            bool iy0 = (lyp - 1u) < 32u, iy1 = lyp < 32u;
            unsigned mask = (unsigned)(ix0 && iy0) | ((unsigned)(ix1 && iy0) << 1)
                          | ((unsigned)(ix0 && iy1) << 2) | ((unsigned)(ix1 && iy1) << 3);
            dmv = lxp | (lyp << 6) | (mask << 12);
            evals[i][0] = q0.x; evals[i][1] = q0.y;
            evals[i][2] = q0.z; evals[i][3] = q0.w;
            evals[i][4] = q1.x; evals[i][5] = q1.y;
            evals[i][6] = q1.z; evals[i][7] = q1.w;
            evals[i][8] = m >> 12;                   // ax10 | ay10<<10
            #pragma unroll
            for (int corner = 0; corner < 4; ++corner) {
                if (mask & (1u << corner)) {
                    int cell = ((int)lyp - 1 + (corner >> 1)) * TS + ((int)lxp - 1 + (corner & 1));
                    atomicAdd(&cnt_s[cell], 1u);
                }
            }
        }
        dm[it] = dmv;
    }
    __syncthreads();

    // --- block prefix scan of 1024 cell counts (2 cells/thread, 8 waves) ---
    unsigned c0 = cnt_s[2 * tid], c1 = cnt_s[2 * tid + 1];
    unsigned s2 = c0 + c1, ps = s2;
    #pragma unroll
    for (int dlt = 1; dlt < 64; dlt <<= 1) {
        unsigned o = __shfl_up(ps, dlt, 64);
        if (lane >= dlt) ps += o;
    }
    if (lane == 63) wscan[wv] = ps;
    __syncthreads();
    if (tid == 0) {
        unsigned a = 0;
        #pragma unroll
        for (int w_ = 0; w_ < 8; ++w_) { unsigned t_ = wscan[w_]; wscan[w_] = a; a += t_; }
    }
    __syncthreads();
    unsigned base = wscan[wv] + ps - s2;
    offs_s[2 * tid]     = (unsigned short)base;        cnt_s[2 * tid]     = base;
    offs_s[2 * tid + 1] = (unsigned short)(base + c0); cnt_s[2 * tid + 1] = base + c0;
    __syncthreads();

    // --- place contributor ids (LDS cursor atomics) ---
    #pragma unroll
    for (int it = 0; it < 3; ++it) {
        int i = it * 512 + tid;
        unsigned dmv = dm[it];
        unsigned mask = dmv >> 12;
        if (i < n && mask) {
            int lxp = (int)(dmv & 63u), lyp = (int)((dmv >> 6) & 63u);
            #pragma unroll
            for (int corner = 0; corner < 4; ++corner) {
                if (mask & (1u << corner)) {
                    int cell = (lyp - 1 + (corner >> 1)) * TS + (lxp - 1 + (corner & 1));
                    unsigned slot = atomicAdd(&cnt_s[cell], 1u);
                    ids[slot] = (unsigned short)((unsigned)i | ((unsigned)corner << 11));
                }
            }
        }
    }
    __syncthreads();

    // --- gather per cell, register accumulate, coalesced plain store ---
    size_t outb = (size_t)b * C * HW;
    #pragma unroll
    for (int j = 0; j < 2; ++j) {
        int cell = tid + 512 * j;
        int cy = cell >> 5, cx = cell & 31;
        float acc[16];
        #pragma unroll
        for (int c = 0; c < 16; ++c) acc[c] = 0.0f;

        int k0 = (int)offs_s[cell];
        int k1 = (int)cnt_s[cell];
        for (int k = k0; k < k1; ++k) {
            unsigned id2 = ids[k];
            unsigned e = id2 & 0x7FFu;
            unsigned corner = id2 >> 11;
            unsigned wt = evals[e][8];
            float ax = (float)(wt & 1023u) * (1.0f / 1024.0f);
            float ay = (float)((wt >> 10) & 1023u) * (1.0f / 1024.0f);
            float fx = (corner & 1u) ? ax : 1.0f - ax;
            float fy = (corner & 2u) ? ay : 1.0f - ay;
            float wgt = fx * fy;
            #pragma unroll
            for (int cp = 0; cp < 8; ++cp) {
                unsigned vwv = evals[e][cp];
                acc[2 * cp]     += wgt * bf_lo(vwv);
                acc[2 * cp + 1] += wgt * bf_hi(vwv);
            }
        }

        float* op0 = out + outb + (size_t)(y0 + cy) * W + (x0 + cx);
        #pragma unroll
        for (int c = 0; c < 16; ++c) op0[(size_t)c * HW] = acc[c];
    }
}

// Phase 3: process overflow side-list (usually empty) AFTER plain stores.
__global__ __launch_bounds__(256) void fixup_kernel(
    const float* __restrict__ flow, const float* __restrict__ im0,
    const unsigned* __restrict__ ovf_cnt, const unsigned* __restrict__ ovf_list,
    float* __restrict__ out)
{
    unsigned n = min(*ovf_cnt, (unsigned)OVF_CAP);
    for (unsigned i = blockIdx.x * 256 + threadIdx.x; i < n; i += gridDim.x * 256) {
        unsigned e = ovf_list[i];
        int b = (int)(e >> 22);
        int s = (int)((e >> 4) & 0x3FFFFu);
        unsigned mask = e & 15u;
        int sx = s & (W - 1), sy = s >> 9;
        float2 f = reinterpret_cast<const float2*>(flow)[(size_t)b * HW + s];
        float xd = (float)sx + f.x, yd = (float)sy + f.y;
        float xff = floorf(xd), yff = floorf(yd);
        int xf = (int)xff, yf = (int)yff;
        float ax = xd - xff, ay = yd - yff;
        float w0 = (1.f - ax) * (1.f - ay), w1 = ax * (1.f - ay);
        float w2 = (1.f - ax) * ay,         w3 = ax * ay;
        direct_splat(im0, out, b, s, xf, yf, w0, w1, w2, w3, mask);
    }
}

// =================== FALLBACK: naive direct-atomic ===================
__global__ __launch_bounds__(256) void warp_naive_kernel(
    const float* __restrict__ im0, const float* __restrict__ flow,
    float* __restrict__ out)
{
    int idx = blockIdx.x * 256 + threadIdx.x;
    if (idx >= B * HW) return;
    int w = idx & (W - 1);
    int h = (idx >> 9) & (H - 1);
    int b = idx >> 18;
    float2 f = reinterpret_cast<const float2*>(flow)[idx];
    float xd = (float)w + f.x, yd = (float)h + f.y;
    float xff = floorf(xd), yff = floorf(yd);
    if (!(xff >= 0.0f && yff >= 0.0f &&
          xff <= (float)(W - 2) && yff <= (float)(H - 2))) return;
    int xf = (int)xff, yf = (int)yff;
    float ax = xd - xff, ay = yd - yff;
    float w0 = (1.f - ax) * (1.f - ay), w1 = ax * (1.f - ay);
    float w2 = (1.f - ax) * ay,         w3 = ax * ay;
    direct_splat(im0, out, b, h * W + w, xf, yf, w0, w1, w2, w3, 15u);
}

extern "C" void kernel_launch(void* const* d_in, const int* in_sizes, int n_in,
                              void* d_out, int out_size, void* d_ws, size_t ws_size,
                              hipStream_t stream) {
    const float* im0  = (const float*)d_in[0];
    const float* flow = (const float*)d_in[1];
    float* out = (float*)d_out;

    // ws layout (u32 words):
    //   cnt[NBINS*CSTR] | ovf_cnt(16) | ovf_list[OVF_CAP] | entm[NBINS*CAP] | entv[NBINS*CAP*8]
    constexpr size_t cnt_words = (size_t)NBINS * CSTR;              // 16384
    constexpr size_t ovf_off   = cnt_words;
    constexpr size_t list_off  = cnt_words + 16;
    constexpr size_t entm_off  = list_off + OVF_CAP;
    constexpr size_t entv_off  = entm_off + (size_t)NBINS * CAP;    // 16B-aligned (x4 words)
    constexpr size_t need      = (entv_off + (size_t)NBINS * CAP * 8) * 4;   // ~47.5 MB
    constexpr int total = B * HW;

    if (ws_size < need) {
        hipMemsetAsync(out, 0, (size_t)out_size * sizeof(float), stream);
        warp_naive_kernel<<<(total + 255) / 256, 256, 0, stream>>>(im0, flow, out);
        return;
    }

    unsigned* cnt      = (unsigned*)d_ws;
    unsigned* ovf_cnt  = cnt + ovf_off;
    unsigned* ovf_list = cnt + list_off;
    unsigned* entm     = cnt + entm_off;
    uint4*    entv     = reinterpret_cast<uint4*>(cnt + entv_off);

    // zero bin counters + overflow counter (no out memset: accum plain-stores
    // every output element; fixup runs after)
    hipMemsetAsync(cnt, 0, list_off * 4, stream);

    bin4_kernel<<<total / 256, 256, 0, stream>>>(flow, im0, cnt, ovf_cnt, ovf_list, entv, entm);
    accum2_kernel<<<NBINS, 512, 0, stream>>>(cnt, entv, entm, out);
    fixup_kernel<<<16, 256, 0, stream>>>(flow, im0, ovf_cnt, ovf_list, out);
}